// Round 8
// baseline (229.608 us; speedup 1.0000x reference)
//
#include <hip/hip_runtime.h>
#include <cstdint>
#include <cstddef>

// ---------------- problem constants (fixed by setup_inputs) ----------------
#define B_  4
#define T_  2048
#define D_  512
#define NH_ 8
#define HD_ 64
#define FF_ 2048
#define M_  (B_*T_)   // 8192 token rows

typedef unsigned short u16;
typedef __attribute__((ext_vector_type(8))) unsigned short u16x8;
typedef __attribute__((ext_vector_type(8))) __bf16         bf16x8;
typedef __attribute__((ext_vector_type(4))) float          f32x4;

__device__ __forceinline__ u16 f2bf(float f) {            // RNE f32 -> bf16
  unsigned u = __float_as_uint(f);
  u += 0x7FFF + ((u >> 16) & 1);
  return (u16)(u >> 16);
}
__device__ __forceinline__ float bf2f(u16 h) {
  return __uint_as_float((unsigned)h << 16);
}

__device__ __forceinline__ f32x4 mfma_bf16(u16x8 a, u16x8 b, f32x4 c) {
  return __builtin_amdgcn_mfma_f32_16x16x32_bf16(
      __builtin_bit_cast(bf16x8, a), __builtin_bit_cast(bf16x8, b), c, 0, 0, 0);
}

// async global->LDS, 16B per lane; LDS dest = wave-uniform base + lane*16
__device__ __forceinline__ void async16(const void* g, void* l) {
  __builtin_amdgcn_global_load_lds(
      (const __attribute__((address_space(1))) unsigned int*)g,
      (__attribute__((address_space(3))) unsigned int*)l, 16, 0, 0);
}

// Branchless GELU via A&S 7.1.26 erf (|err| <= 1.5e-7).
__device__ __forceinline__ float gelu_f(float v) {
  float ax = fabsf(v) * 0.70710678118f;
  float t = 1.0f / (1.0f + 0.3275911f * ax);
  float p = ((((1.061405429f * t - 1.453152027f) * t + 1.421413741f) * t
              - 0.284496736f) * t + 0.254829592f) * t;
  float e = __expf(-ax * ax);
  float er = 1.0f - p * e;
  float s = (v >= 0.0f) ? er : -er;
  return 0.5f * v * (1.0f + s);
}

// ---- merged transpose + cast for all 4 weights in ONE launch.
__global__ __launch_bounds__(256) void trans4_kernel(
    const float* __restrict__ i0, u16* __restrict__ o0,   // wqkv 512x1536
    const float* __restrict__ i1, u16* __restrict__ o1,   // wout 512x512
    const float* __restrict__ i2, u16* __restrict__ o2,   // w1   512x2048
    const float* __restrict__ i3, u16* __restrict__ o3) { // w2   2048x512
  __shared__ float tile[32][33];
  int bid = blockIdx.x;
  const float* in; u16* out; int R, C, gx, lb;
  if (bid < 768)       { in = i0; out = o0; R = 512;  C = 1536; gx = 48; lb = bid; }
  else if (bid < 1024) { in = i1; out = o1; R = 512;  C = 512;  gx = 16; lb = bid - 768; }
  else if (bid < 2048) { in = i2; out = o2; R = 512;  C = 2048; gx = 64; lb = bid - 1024; }
  else                 { in = i3; out = o3; R = 2048; C = 512;  gx = 16; lb = bid - 2048; }
  int c0 = (lb % gx) * 32, r0 = (lb / gx) * 32;
  int tx = threadIdx.x, ty = threadIdx.y;  // block (32,8)
#pragma unroll
  for (int i = 0; i < 4; i++)
    tile[ty + i * 8][tx] = in[(size_t)(r0 + ty + i * 8) * C + c0 + tx];
  __syncthreads();
#pragma unroll
  for (int i = 0; i < 4; i++)
    out[(size_t)(c0 + ty + i * 8) * R + r0 + tx] = f2bf(tile[tx][ty + i * 8]);
}

// ---- rmsnorm over rows of 512, f32 or bf16 in -> bf16 out. 1 wave per row.
// Optionally also emits the RAW input row cast to bf16 (for bf16 residuals).
template <bool INBF>
__global__ __launch_bounds__(256) void rmsnorm_kernel(const void* __restrict__ xv,
                                                      const float* __restrict__ w,
                                                      u16* __restrict__ out,
                                                      u16* __restrict__ rawout) {
  int row  = blockIdx.x * 4 + (threadIdx.x >> 6);
  int lane = threadIdx.x & 63;
  float v[8];
  if (INBF) {
    u16x8 raw = *(const u16x8*)((const u16*)xv + (size_t)row * D_ + lane * 8);
#pragma unroll
    for (int e = 0; e < 8; e++) v[e] = bf2f(raw[e]);
  } else {
    const float* xr = (const float*)xv + (size_t)row * D_ + lane * 8;
    *(float4*)(v)     = *(const float4*)xr;
    *(float4*)(v + 4) = *(const float4*)(xr + 4);
  }
  if (rawout) {
    u16 rw[8];
#pragma unroll
    for (int e = 0; e < 8; e++) rw[e] = f2bf(v[e]);
    *(uint4*)(rawout + (size_t)row * D_ + lane * 8) = *(uint4*)rw;
  }
  float ss = 0.f;
#pragma unroll
  for (int e = 0; e < 8; e++) ss += v[e] * v[e];
#pragma unroll
  for (int m = 1; m < 64; m <<= 1) ss += __shfl_xor(ss, m, 64);
  float inv = rsqrtf(ss * (1.0f / D_) + 1e-6f);
  const float* wr = w + lane * 8;
  float wv[8];
  *(float4*)(wv)     = *(const float4*)wr;
  *(float4*)(wv + 4) = *(const float4*)(wr + 4);
  u16 o[8];
#pragma unroll
  for (int e = 0; e < 8; e++) o[e] = f2bf(v[e] * inv * wv[e]);
  *(uint4*)(out + (size_t)row * D_ + lane * 8) = *(uint4*)o;
}

// ---- bf16 MFMA GEMM: C[M,N] = A[M,K] * Bt[N,K]^T (+bias)(gelu)(+res)
// BM x BN tile, BK=32, DOUBLE-BUFFERED LDS (12 KB/stage for 64x128 ->
// 24 KB total -> 6 blocks/CU). Prefetch t+1 issued after the barrier so
// compute(t) covers its latency; one barrier per kt.
// 256 threads = 4 waves (2x2), wave tile (BM/2)x(BN/2). XOR-swizzled LDS:
// 16B chunk c (of 4) of row r lives at physical slot c^(r&3).
// RES_MODE: 0 none, 1 f32, 2 bf16.
template <int BM, int BN, bool HAS_BIAS, int RES_MODE, bool DO_GELU, bool STORE_BF16>
__global__ __launch_bounds__(256) void gemm_kernel(
    const u16* __restrict__ A, const u16* __restrict__ Bt, void* __restrict__ Cv,
    const float* __restrict__ bias, const void* __restrict__ resv,
    int M, int N, int K) {
  constexpr int ACH = BM / 64;              // A staging chunks (64 rows each)
  constexpr int BCH = BN / 64;              // B staging chunks
  constexpr int WM  = BM / 2, WN = BN / 2;  // per-wave tile
  constexpr int MI  = WM / 16, NJ = WN / 16;
  constexpr int EW  = BN + 4;               // epilogue LDS row pitch (f32)
  constexpr int STG = (BM + BN) * 64;       // bytes per stage buffer (A+B)
  constexpr int EPB = 32 * EW * 4;          // epilogue bytes
  constexpr int SMB = (2 * STG > EPB) ? 2 * STG : EPB;
  __shared__ __align__(16) char smem[SMB];
  const int tid = threadIdx.x;
  const int lane = tid & 63, w = tid >> 6;
  const int quad = lane >> 4, m16 = lane & 15;
  const int wm = w & 1, wn = w >> 1;
  const int m0 = blockIdx.y * BM, n0 = blockIdx.x * BN;

  f32x4 acc[MI][NJ];
#pragma unroll
  for (int i = 0; i < MI; i++)
#pragma unroll
    for (int j = 0; j < NJ; j++) acc[i][j] = (f32x4){0.f, 0.f, 0.f, 0.f};

  const int srow = tid >> 2;                       // 0..63
  const int scol = (((tid & 3) ^ (srow & 3))) * 8; // swizzled source k-chunk
  const u16* Ag = A  + (size_t)(m0 + srow) * K + scol;
  const u16* Bg = Bt + (size_t)(n0 + srow) * K + scol;

  auto stage = [&](int buf, int kt) {
    char* base = smem + buf * STG;
#pragma unroll
    for (int c = 0; c < ACH; c++)
      async16(Ag + (size_t)c * 64 * K + kt, base + c * 4096 + tid * 16);
#pragma unroll
    for (int c = 0; c < BCH; c++)
      async16(Bg + (size_t)c * 64 * K + kt, base + BM * 64 + c * 4096 + tid * 16);
  };
  auto compute = [&](int buf) {
    const u16* lA = (const u16*)(smem + buf * STG);
    const u16* lB = (const u16*)(smem + buf * STG + BM * 64);
    const int sl = (quad ^ (m16 & 3)) * 8;         // physical 16B slot
    const u16* pa = lA + (wm * WM + m16) * 32 + sl;
    const u16* pb = lB + (wn * WN + m16) * 32 + sl;
    u16x8 af[MI], bfr[NJ];
#pragma unroll
    for (int i = 0; i < MI; i++) af[i] = *(const u16x8*)(pa + i * 512);
#pragma unroll
    for (int j = 0; j < NJ; j++) bfr[j] = *(const u16x8*)(pb + j * 512);
#pragma unroll
    for (int i = 0; i < MI; i++)
#pragma unroll
      for (int j = 0; j < NJ; j++)
        acc[i][j] = mfma_bf16(af[i], bfr[j], acc[i][j]);
  };

  const int nk = K >> 5;
  stage(0, 0);
  for (int t = 0; t < nk; t++) {
    __syncthreads();                // drains stage(t); covered by compute(t-1)
    if (t + 1 < nk) stage((t + 1) & 1, (t + 1) << 5);
    compute(t & 1);
  }

  // ---- epilogue: stage 32 rows x BN cols f32 in LDS per i-step, then
  // read back row-major and store full vectors (no partial lines).
  float* eps = (float*)smem;
  constexpr int REPS = (32 * BN) / (256 * 8);   // 2 for BN=128, 1 for BN=64
  float bv[REPS > 0 ? REPS : 1][8];
  if (HAS_BIAS) {
#pragma unroll
    for (int rep = 0; rep < REPS; rep++) {
      const int col = (BN == 128) ? ((tid & 15) * 8) : ((tid & 7) * 8);
      *(float4*)(bv[rep])     = *(const float4*)(bias + n0 + col);
      *(float4*)(bv[rep] + 4) = *(const float4*)(bias + n0 + col + 4);
    }
  }
#pragma unroll
  for (int i = 0; i < MI; i++) {
    __syncthreads();
#pragma unroll
    for (int j = 0; j < NJ; j++)
#pragma unroll
      for (int r = 0; r < 4; r++)
        eps[(wm * 16 + quad * 4 + r) * EW + wn * WN + j * 16 + m16] =
            acc[i][j][r];
    __syncthreads();
#pragma unroll
    for (int rep = 0; rep < REPS; rep++) {
      const int lr  = (BN == 128) ? (rep * 16 + (tid >> 4)) : (tid >> 3);
      const int col = (BN == 128) ? ((tid & 15) * 8) : ((tid & 7) * 8);
      const int rg  = m0 + (lr >> 4) * WM + i * 16 + (lr & 15);
      float v[8];
      *(float4*)(v)     = *(const float4*)(eps + lr * EW + col);
      *(float4*)(v + 4) = *(const float4*)(eps + lr * EW + col + 4);
      if (HAS_BIAS) {
#pragma unroll
        for (int e = 0; e < 8; e++) v[e] += bv[rep][e];
      }
      if (DO_GELU) {
#pragma unroll
        for (int e = 0; e < 8; e++) v[e] = gelu_f(v[e]);
      }
      const size_t idx = (size_t)rg * N + n0 + col;
      if (RES_MODE == 1) {
        float4 r0 = *(const float4*)((const float*)resv + idx);
        float4 r1 = *(const float4*)((const float*)resv + idx + 4);
        v[0] += r0.x; v[1] += r0.y; v[2] += r0.z; v[3] += r0.w;
        v[4] += r1.x; v[5] += r1.y; v[6] += r1.z; v[7] += r1.w;
      } else if (RES_MODE == 2) {
        u16x8 rr = *(const u16x8*)((const u16*)resv + idx);
#pragma unroll
        for (int e = 0; e < 8; e++) v[e] += bf2f(rr[e]);
      }
      if (STORE_BF16) {
        u16 o[8];
#pragma unroll
        for (int e = 0; e < 8; e++) o[e] = f2bf(v[e]);
        *(uint4*)((u16*)Cv + idx) = *(uint4*)o;
      } else {
        *(float4*)((float*)Cv + idx)     = *(float4*)(v);
        *(float4*)((float*)Cv + idx + 4) = *(float4*)(v + 4);
      }
    }
  }
}

// ---- banded attention, MFMA flash-style, full-window softmax in registers.
#define KP_ 72
#define VP_ 218
__global__ __launch_bounds__(256) void attn_kernel(const u16* __restrict__ qkv,
                                                   u16* __restrict__ out) {
  __shared__ __align__(16) char smem[29952 + 64 * VP_ * 2];
  u16* Ks = (u16*)smem;               // [208][72] keys (29952 B)
  u16* Vt = (u16*)(smem + 29952);     // [64][218] V transposed
  const int tid = threadIdx.x, lane = tid & 63, w = tid >> 6;
  const int quad = lane >> 4, m16 = lane & 15;
  const int q0 = blockIdx.x * 64, h = blockIdx.y, b = blockIdx.z;
  const int kstart = q0 - 64;         // 208-key staging window
  const u16* base = qkv + (size_t)b * T_ * 1536;

  for (int c = tid; c < 1664; c += 256) {
    int row = c >> 3, cc = (c & 7) * 8;
    int j = kstart + row;
    j = j < 0 ? 0 : (j > T_ - 1 ? T_ - 1 : j);   // clamp; masked later
    *(uint4*)(Ks + row * KP_ + cc) =
        *(const uint4*)(base + (size_t)j * 1536 + 512 + h * 64 + cc);
  }
  for (int c = tid; c < 1664; c += 256) {
    int row = c >> 3, cc = (c & 7) * 8;
    int j = kstart + row;
    j = j < 0 ? 0 : (j > T_ - 1 ? T_ - 1 : j);
    uint4 u = *(const uint4*)(base + (size_t)j * 1536 + 1024 + h * 64 + cc);
    u16 tmp[8];
    *(uint4*)tmp = u;
#pragma unroll
    for (int i = 0; i < 8; i++) Vt[(cc + i) * VP_ + row] = tmp[i];
  }
  const int qw = q0 + w * 16;
  const u16* qb = base + (size_t)(qw + m16) * 1536 + h * 64 + quad * 8;
  u16x8 a0 = *(const u16x8*)qb;
  u16x8 a1 = *(const u16x8*)(qb + 32);
  __syncthreads();

  float s[10][4];
#pragma unroll
  for (int t = 0; t < 10; t++) {
    int kt = (w + t) * 16;
    u16x8 kb0 = *(const u16x8*)(Ks + (kt + m16) * KP_ + quad * 8);
    u16x8 kb1 = *(const u16x8*)(Ks + (kt + m16) * KP_ + 32 + quad * 8);
    f32x4 acc = {0.f, 0.f, 0.f, 0.f};
    acc = mfma_bf16(a0, kb0, acc);
    acc = mfma_bf16(a1, kb1, acc);
    int jab = kstart + kt + m16;
#pragma unroll
    for (int r = 0; r < 4; r++) {
      int q = qw + quad * 4 + r;
      int d = q - jab;
      bool valid = (jab >= 0) && (jab < T_) && (d <= 64) && (d >= -64);
      s[t][r] = valid ? acc[r] * 0.125f : -1e30f;
    }
  }
  float mx[4], sm[4];
#pragma unroll
  for (int r = 0; r < 4; r++) mx[r] = -1e30f;
#pragma unroll
  for (int t = 0; t < 10; t++)
#pragma unroll
    for (int r = 0; r < 4; r++) mx[r] = fmaxf(mx[r], s[t][r]);
#pragma unroll
  for (int r = 0; r < 4; r++) {
#pragma unroll
    for (int msk = 1; msk < 16; msk <<= 1)
      mx[r] = fmaxf(mx[r], __shfl_xor(mx[r], msk, 64));
    sm[r] = 0.f;
  }
#pragma unroll
  for (int t = 0; t < 10; t++)
#pragma unroll
    for (int r = 0; r < 4; r++) {
      float e = __expf(s[t][r] - mx[r]);
      s[t][r] = e; sm[r] += e;
    }
#pragma unroll
  for (int r = 0; r < 4; r++) {
#pragma unroll
    for (int msk = 1; msk < 16; msk <<= 1) sm[r] += __shfl_xor(sm[r], msk, 64);
    sm[r] = 1.0f / sm[r];
  }
  __syncthreads();
  u16* Ps = (u16*)smem + w * 2688;       // alias Ks region: per-wave [16][168]
#pragma unroll
  for (int t = 0; t < 10; t++)
#pragma unroll
    for (int r = 0; r < 4; r++)
      Ps[(quad * 4 + r) * 168 + t * 16 + m16] = f2bf(s[t][r] * sm[r]);
  __syncthreads();

  f32x4 o[4];
#pragma unroll
  for (int dt = 0; dt < 4; dt++) o[dt] = (f32x4){0.f, 0.f, 0.f, 0.f};
#pragma unroll
  for (int c5 = 0; c5 < 5; c5++) {
    u16x8 pa = *(const u16x8*)(Ps + m16 * 168 + c5 * 32 + quad * 8);
#pragma unroll
    for (int dt = 0; dt < 4; dt++) {
      u16x8 vb = *(const u16x8*)(Vt + (dt * 16 + m16) * VP_ + w * 16 + c5 * 32 + quad * 8);
      o[dt] = mfma_bf16(pa, vb, o[dt]);
    }
  }
#pragma unroll
  for (int dt = 0; dt < 4; dt++)
#pragma unroll
    for (int r = 0; r < 4; r++)
      out[(size_t)(b * T_ + qw + quad * 4 + r) * D_ + h * HD_ + dt * 16 + m16] =
          f2bf(o[dt][r]);
}

// ---------------------------------------------------------------------------
extern "C" void kernel_launch(void* const* d_in, const int* in_sizes, int n_in,
                              void* d_out, int out_size, void* d_ws, size_t ws_size,
                              hipStream_t stream) {
  (void)in_sizes; (void)n_in; (void)out_size; (void)ws_size;
  const float* x     = (const float*)d_in[0];
  const float* n1w   = (const float*)d_in[1];
  const float* n2w   = (const float*)d_in[2];
  const float* w_qkv = (const float*)d_in[3];
  const float* w_out = (const float*)d_in[4];
  const float* b_out = (const float*)d_in[5];
  const float* w1    = (const float*)d_in[6];
  const float* b1    = (const float*)d_in[7];
  const float* w2    = (const float*)d_in[8];
  const float* b2    = (const float*)d_in[9];
  float* out = (float*)d_out;
  char* ws = (char*)d_ws;

  // workspace layout (x1 bf16; hbuf aliases dead qkv+attno, hn aliases xn)
  u16* wqkvT  = (u16*)(ws + 0);          // [1536][512]  1.5 MB
  u16* woutT  = (u16*)(ws + 1572864);    // [512][512]   0.5 MB
  u16* w1T    = (u16*)(ws + 2097152);    // [2048][512]  2 MB
  u16* w2T    = (u16*)(ws + 4194304);    // [512][2048]  2 MB
  u16* xn     = (u16*)(ws + 6291456);    // [8192][512]  8 MB (also hn)
  u16* qkv    = (u16*)(ws + 14680064);   // [8192][1536] 24 MB
  u16* attno  = (u16*)(ws + 39845888);   // [8192][512]  8 MB
  u16* x1     = (u16*)(ws + 48234496);   // [8192][512]  8 MB bf16
  u16* xbf    = (u16*)(ws + 56623104);   // [8192][512]  8 MB bf16 (raw x)
  u16* hn     = xn;
  u16* hbuf   = qkv;                     // [8192][2048] 32 MB (over qkv+attno)

  trans4_kernel<<<3072, dim3(32, 8), 0, stream>>>(
      w_qkv, wqkvT, w_out, woutT, w1, w1T, w2, w2T);

  // rms1 also emits raw x as bf16 for the w_out residual
  rmsnorm_kernel<false><<<2048, 256, 0, stream>>>(x, n1w, xn, xbf);
  gemm_kernel<64, 128, false, 0, false, true><<<dim3(12, 128), 256, 0, stream>>>(
      xn, wqkvT, (void*)qkv, nullptr, nullptr, M_, 3 * D_, D_);
  attn_kernel<<<dim3(32, 8, 4), 256, 0, stream>>>(qkv, attno);
  // x1 = attno @ w_out + b_out + xbf   (bf16 out, bf16 res)
  gemm_kernel<64, 128, true, 2, false, true><<<dim3(4, 128), 256, 0, stream>>>(
      attno, woutT, (void*)x1, b_out, xbf, M_, D_, D_);
  rmsnorm_kernel<true><<<2048, 256, 0, stream>>>(x1, n2w, hn, nullptr);
  gemm_kernel<64, 128, true, 0, true, true><<<dim3(16, 128), 256, 0, stream>>>(
      hn, w1T, (void*)hbuf, b1, nullptr, M_, FF_, D_);
  // out = hbuf @ w2 + b2 + x1   (f32 out, bf16 res)
  gemm_kernel<64, 128, true, 2, false, false><<<dim3(4, 128), 256, 0, stream>>>(
      hbuf, w2T, (void*)out, b2, x1, M_, D_, FF_);
}

// Round 9
// 223.117 us; speedup vs baseline: 1.0291x; 1.0291x over previous
//
#include <hip/hip_runtime.h>
#include <cstdint>
#include <cstddef>

// ---------------- problem constants (fixed by setup_inputs) ----------------
#define B_  4
#define T_  2048
#define D_  512
#define NH_ 8
#define HD_ 64
#define FF_ 2048
#define M_  (B_*T_)   // 8192 token rows

typedef unsigned short u16;
typedef __attribute__((ext_vector_type(8))) unsigned short u16x8;
typedef __attribute__((ext_vector_type(8))) __bf16         bf16x8;
typedef __attribute__((ext_vector_type(4))) float          f32x4;

__device__ __forceinline__ u16 f2bf(float f) {            // RNE f32 -> bf16
  unsigned u = __float_as_uint(f);
  u += 0x7FFF + ((u >> 16) & 1);
  return (u16)(u >> 16);
}
__device__ __forceinline__ float bf2f(u16 h) {
  return __uint_as_float((unsigned)h << 16);
}

__device__ __forceinline__ f32x4 mfma_bf16(u16x8 a, u16x8 b, f32x4 c) {
  return __builtin_amdgcn_mfma_f32_16x16x32_bf16(
      __builtin_bit_cast(bf16x8, a), __builtin_bit_cast(bf16x8, b), c, 0, 0, 0);
}

// async global->LDS, 16B per lane; LDS dest = wave-uniform base + lane*16
__device__ __forceinline__ void async16(const void* g, void* l) {
  __builtin_amdgcn_global_load_lds(
      (const __attribute__((address_space(1))) unsigned int*)g,
      (__attribute__((address_space(3))) unsigned int*)l, 16, 0, 0);
}

// Branchless GELU via A&S 7.1.26 erf (|err| <= 1.5e-7).
__device__ __forceinline__ float gelu_f(float v) {
  float ax = fabsf(v) * 0.70710678118f;
  float t = 1.0f / (1.0f + 0.3275911f * ax);
  float p = ((((1.061405429f * t - 1.453152027f) * t + 1.421413741f) * t
              - 0.284496736f) * t + 0.254829592f) * t;
  float e = __expf(-ax * ax);
  float er = 1.0f - p * e;
  float s = (v >= 0.0f) ? er : -er;
  return 0.5f * v * (1.0f + s);
}

// ---- merged transpose + cast for all 4 weights in ONE launch.
__global__ __launch_bounds__(256) void trans4_kernel(
    const float* __restrict__ i0, u16* __restrict__ o0,   // wqkv 512x1536
    const float* __restrict__ i1, u16* __restrict__ o1,   // wout 512x512
    const float* __restrict__ i2, u16* __restrict__ o2,   // w1   512x2048
    const float* __restrict__ i3, u16* __restrict__ o3) { // w2   2048x512
  __shared__ float tile[32][33];
  int bid = blockIdx.x;
  const float* in; u16* out; int R, C, gx, lb;
  if (bid < 768)       { in = i0; out = o0; R = 512;  C = 1536; gx = 48; lb = bid; }
  else if (bid < 1024) { in = i1; out = o1; R = 512;  C = 512;  gx = 16; lb = bid - 768; }
  else if (bid < 2048) { in = i2; out = o2; R = 512;  C = 2048; gx = 64; lb = bid - 1024; }
  else                 { in = i3; out = o3; R = 2048; C = 512;  gx = 16; lb = bid - 2048; }
  int c0 = (lb % gx) * 32, r0 = (lb / gx) * 32;
  int tx = threadIdx.x, ty = threadIdx.y;  // block (32,8)
#pragma unroll
  for (int i = 0; i < 4; i++)
    tile[ty + i * 8][tx] = in[(size_t)(r0 + ty + i * 8) * C + c0 + tx];
  __syncthreads();
#pragma unroll
  for (int i = 0; i < 4; i++)
    out[(size_t)(c0 + ty + i * 8) * R + r0 + tx] = f2bf(tile[tx][ty + i * 8]);
}

// ---- rmsnorm over rows of 512, f32 or bf16 in -> bf16 out. 1 wave per row.
// Optionally also emits the RAW input row cast to bf16 (for bf16 residuals).
template <bool INBF>
__global__ __launch_bounds__(256) void rmsnorm_kernel(const void* __restrict__ xv,
                                                      const float* __restrict__ w,
                                                      u16* __restrict__ out,
                                                      u16* __restrict__ rawout) {
  int row  = blockIdx.x * 4 + (threadIdx.x >> 6);
  int lane = threadIdx.x & 63;
  float v[8];
  if (INBF) {
    u16x8 raw = *(const u16x8*)((const u16*)xv + (size_t)row * D_ + lane * 8);
#pragma unroll
    for (int e = 0; e < 8; e++) v[e] = bf2f(raw[e]);
  } else {
    const float* xr = (const float*)xv + (size_t)row * D_ + lane * 8;
    *(float4*)(v)     = *(const float4*)xr;
    *(float4*)(v + 4) = *(const float4*)(xr + 4);
  }
  if (rawout) {
    u16 rw[8];
#pragma unroll
    for (int e = 0; e < 8; e++) rw[e] = f2bf(v[e]);
    *(uint4*)(rawout + (size_t)row * D_ + lane * 8) = *(uint4*)rw;
  }
  float ss = 0.f;
#pragma unroll
  for (int e = 0; e < 8; e++) ss += v[e] * v[e];
#pragma unroll
  for (int m = 1; m < 64; m <<= 1) ss += __shfl_xor(ss, m, 64);
  float inv = rsqrtf(ss * (1.0f / D_) + 1e-6f);
  const float* wr = w + lane * 8;
  float wv[8];
  *(float4*)(wv)     = *(const float4*)wr;
  *(float4*)(wv + 4) = *(const float4*)(wr + 4);
  u16 o[8];
#pragma unroll
  for (int e = 0; e < 8; e++) o[e] = f2bf(v[e] * inv * wv[e]);
  *(uint4*)(out + (size_t)row * D_ + lane * 8) = *(uint4*)o;
}

// ---- bf16 MFMA GEMM: C[M,N] = A[M,K] * Bt[N,K]^T (+bias)(gelu)(+res)
// BM x BN tile, BK=64, DOUBLE-BUFFERED LDS (round-7 proven config:
// 24 KB/stage for 64x128 -> 48 KB total -> 3 blocks/CU, 16 MFMA/barrier).
// BK=32 variant measured WORSE (R8: 2x barriers, half work each) — keep 64.
// Prefetch t+1 issued after the barrier so compute(t) covers its latency.
// 256 threads = 4 waves (2x2), wave tile (BM/2)x(BN/2). XOR-swizzled LDS:
// 16B chunk c (of 8) of row r lives at physical slot c^(r&7).
// RES_MODE: 0 none, 1 f32, 2 bf16.
template <int BM, int BN, bool HAS_BIAS, int RES_MODE, bool DO_GELU, bool STORE_BF16>
__global__ __launch_bounds__(256) void gemm_kernel(
    const u16* __restrict__ A, const u16* __restrict__ Bt, void* __restrict__ Cv,
    const float* __restrict__ bias, const void* __restrict__ resv,
    int M, int N, int K) {
  constexpr int ACH = BM / 32;              // A staging chunks (32 rows each)
  constexpr int BCH = BN / 32;              // B staging chunks
  constexpr int WM  = BM / 2, WN = BN / 2;  // per-wave tile
  constexpr int MI  = WM / 16, NJ = WN / 16;
  constexpr int EW  = BN + 4;               // epilogue LDS row pitch (f32)
  constexpr int STG = (BM + BN) * 128;      // bytes per stage buffer (A+B)
  constexpr int EPB = 32 * EW * 4;          // epilogue bytes
  constexpr int SMB = (2 * STG > EPB) ? 2 * STG : EPB;
  __shared__ __align__(16) char smem[SMB];
  const int tid = threadIdx.x;
  const int lane = tid & 63, w = tid >> 6;
  const int quad = lane >> 4, m16 = lane & 15;
  const int wm = w & 1, wn = w >> 1;
  const int m0 = blockIdx.y * BM, n0 = blockIdx.x * BN;

  f32x4 acc[MI][NJ];
#pragma unroll
  for (int i = 0; i < MI; i++)
#pragma unroll
    for (int j = 0; j < NJ; j++) acc[i][j] = (f32x4){0.f, 0.f, 0.f, 0.f};

  const int srow = tid >> 3;                       // 0..31
  const int scol = (((tid & 7) ^ (srow & 7))) * 8; // swizzled source k-chunk
  const u16* Ag = A  + (size_t)(m0 + srow) * K + scol;
  const u16* Bg = Bt + (size_t)(n0 + srow) * K + scol;

  auto stage = [&](int buf, int kt) {
    char* base = smem + buf * STG;
#pragma unroll
    for (int c = 0; c < ACH; c++)
      async16(Ag + (size_t)c * 32 * K + kt, base + c * 4096 + tid * 16);
#pragma unroll
    for (int c = 0; c < BCH; c++)
      async16(Bg + (size_t)c * 32 * K + kt, base + BM * 128 + c * 4096 + tid * 16);
  };
  auto compute = [&](int buf) {
    const u16* lA = (const u16*)(smem + buf * STG);
    const u16* lB = (const u16*)(smem + buf * STG + BM * 128);
#pragma unroll
    for (int kk = 0; kk < 2; kk++) {
      const int sl = ((kk * 4 + quad) ^ (m16 & 7)) * 8;  // physical slot
      const u16* pa = lA + (wm * WM + m16) * 64 + sl;
      const u16* pb = lB + (wn * WN + m16) * 64 + sl;
      u16x8 af[MI], bfr[NJ];
#pragma unroll
      for (int i = 0; i < MI; i++) af[i] = *(const u16x8*)(pa + i * 1024);
#pragma unroll
      for (int j = 0; j < NJ; j++) bfr[j] = *(const u16x8*)(pb + j * 1024);
#pragma unroll
      for (int i = 0; i < MI; i++)
#pragma unroll
        for (int j = 0; j < NJ; j++)
          acc[i][j] = mfma_bf16(af[i], bfr[j], acc[i][j]);
    }
  };

  const int nk = K >> 6;
  stage(0, 0);
  for (int t = 0; t < nk; t++) {
    __syncthreads();                // drains stage(t); covered by compute(t-1)
    if (t + 1 < nk) stage((t + 1) & 1, (t + 1) << 6);
    compute(t & 1);
  }

  // ---- epilogue: stage 32 rows x BN cols f32 in LDS per i-step, then
  // read back row-major and store full vectors (no partial lines).
  float* eps = (float*)smem;
  constexpr int REPS = (32 * BN) / (256 * 8);   // 2 for BN=128, 1 for BN=64
  float bv[REPS > 0 ? REPS : 1][8];
  if (HAS_BIAS) {
#pragma unroll
    for (int rep = 0; rep < REPS; rep++) {
      const int col = (BN == 128) ? ((tid & 15) * 8) : ((tid & 7) * 8);
      *(float4*)(bv[rep])     = *(const float4*)(bias + n0 + col);
      *(float4*)(bv[rep] + 4) = *(const float4*)(bias + n0 + col + 4);
    }
  }
#pragma unroll
  for (int i = 0; i < MI; i++) {
    __syncthreads();
#pragma unroll
    for (int j = 0; j < NJ; j++)
#pragma unroll
      for (int r = 0; r < 4; r++)
        eps[(wm * 16 + quad * 4 + r) * EW + wn * WN + j * 16 + m16] =
            acc[i][j][r];
    __syncthreads();
#pragma unroll
    for (int rep = 0; rep < REPS; rep++) {
      const int lr  = (BN == 128) ? (rep * 16 + (tid >> 4)) : (tid >> 3);
      const int col = (BN == 128) ? ((tid & 15) * 8) : ((tid & 7) * 8);
      const int rg  = m0 + (lr >> 4) * WM + i * 16 + (lr & 15);
      float v[8];
      *(float4*)(v)     = *(const float4*)(eps + lr * EW + col);
      *(float4*)(v + 4) = *(const float4*)(eps + lr * EW + col + 4);
      if (HAS_BIAS) {
#pragma unroll
        for (int e = 0; e < 8; e++) v[e] += bv[rep][e];
      }
      if (DO_GELU) {
#pragma unroll
        for (int e = 0; e < 8; e++) v[e] = gelu_f(v[e]);
      }
      const size_t idx = (size_t)rg * N + n0 + col;
      if (RES_MODE == 1) {
        float4 r0 = *(const float4*)((const float*)resv + idx);
        float4 r1 = *(const float4*)((const float*)resv + idx + 4);
        v[0] += r0.x; v[1] += r0.y; v[2] += r0.z; v[3] += r0.w;
        v[4] += r1.x; v[5] += r1.y; v[6] += r1.z; v[7] += r1.w;
      } else if (RES_MODE == 2) {
        u16x8 rr = *(const u16x8*)((const u16*)resv + idx);
#pragma unroll
        for (int e = 0; e < 8; e++) v[e] += bf2f(rr[e]);
      }
      if (STORE_BF16) {
        u16 o[8];
#pragma unroll
        for (int e = 0; e < 8; e++) o[e] = f2bf(v[e]);
        *(uint4*)((u16*)Cv + idx) = *(uint4*)o;
      } else {
        *(float4*)((float*)Cv + idx)     = *(float4*)(v);
        *(float4*)((float*)Cv + idx + 4) = *(float4*)(v + 4);
      }
    }
  }
}

// ---- banded attention, MFMA flash-style, full-window softmax in registers.
#define KP_ 72
#define VP_ 218
__global__ __launch_bounds__(256) void attn_kernel(const u16* __restrict__ qkv,
                                                   u16* __restrict__ out) {
  __shared__ __align__(16) char smem[29952 + 64 * VP_ * 2];
  u16* Ks = (u16*)smem;               // [208][72] keys (29952 B)
  u16* Vt = (u16*)(smem + 29952);     // [64][218] V transposed
  const int tid = threadIdx.x, lane = tid & 63, w = tid >> 6;
  const int quad = lane >> 4, m16 = lane & 15;
  const int q0 = blockIdx.x * 64, h = blockIdx.y, b = blockIdx.z;
  const int kstart = q0 - 64;         // 208-key staging window
  const u16* base = qkv + (size_t)b * T_ * 1536;

  for (int c = tid; c < 1664; c += 256) {
    int row = c >> 3, cc = (c & 7) * 8;
    int j = kstart + row;
    j = j < 0 ? 0 : (j > T_ - 1 ? T_ - 1 : j);   // clamp; masked later
    *(uint4*)(Ks + row * KP_ + cc) =
        *(const uint4*)(base + (size_t)j * 1536 + 512 + h * 64 + cc);
  }
  for (int c = tid; c < 1664; c += 256) {
    int row = c >> 3, cc = (c & 7) * 8;
    int j = kstart + row;
    j = j < 0 ? 0 : (j > T_ - 1 ? T_ - 1 : j);
    uint4 u = *(const uint4*)(base + (size_t)j * 1536 + 1024 + h * 64 + cc);
    u16 tmp[8];
    *(uint4*)tmp = u;
#pragma unroll
    for (int i = 0; i < 8; i++) Vt[(cc + i) * VP_ + row] = tmp[i];
  }
  const int qw = q0 + w * 16;
  const u16* qb = base + (size_t)(qw + m16) * 1536 + h * 64 + quad * 8;
  u16x8 a0 = *(const u16x8*)qb;
  u16x8 a1 = *(const u16x8*)(qb + 32);
  __syncthreads();

  float s[10][4];
#pragma unroll
  for (int t = 0; t < 10; t++) {
    int kt = (w + t) * 16;
    u16x8 kb0 = *(const u16x8*)(Ks + (kt + m16) * KP_ + quad * 8);
    u16x8 kb1 = *(const u16x8*)(Ks + (kt + m16) * KP_ + 32 + quad * 8);
    f32x4 acc = {0.f, 0.f, 0.f, 0.f};
    acc = mfma_bf16(a0, kb0, acc);
    acc = mfma_bf16(a1, kb1, acc);
    int jab = kstart + kt + m16;
#pragma unroll
    for (int r = 0; r < 4; r++) {
      int q = qw + quad * 4 + r;
      int d = q - jab;
      bool valid = (jab >= 0) && (jab < T_) && (d <= 64) && (d >= -64);
      s[t][r] = valid ? acc[r] * 0.125f : -1e30f;
    }
  }
  float mx[4], sm[4];
#pragma unroll
  for (int r = 0; r < 4; r++) mx[r] = -1e30f;
#pragma unroll
  for (int t = 0; t < 10; t++)
#pragma unroll
    for (int r = 0; r < 4; r++) mx[r] = fmaxf(mx[r], s[t][r]);
#pragma unroll
  for (int r = 0; r < 4; r++) {
#pragma unroll
    for (int msk = 1; msk < 16; msk <<= 1)
      mx[r] = fmaxf(mx[r], __shfl_xor(mx[r], msk, 64));
    sm[r] = 0.f;
  }
#pragma unroll
  for (int t = 0; t < 10; t++)
#pragma unroll
    for (int r = 0; r < 4; r++) {
      float e = __expf(s[t][r] - mx[r]);
      s[t][r] = e; sm[r] += e;
    }
#pragma unroll
  for (int r = 0; r < 4; r++) {
#pragma unroll
    for (int msk = 1; msk < 16; msk <<= 1) sm[r] += __shfl_xor(sm[r], msk, 64);
    sm[r] = 1.0f / sm[r];
  }
  __syncthreads();
  u16* Ps = (u16*)smem + w * 2688;       // alias Ks region: per-wave [16][168]
#pragma unroll
  for (int t = 0; t < 10; t++)
#pragma unroll
    for (int r = 0; r < 4; r++)
      Ps[(quad * 4 + r) * 168 + t * 16 + m16] = f2bf(s[t][r] * sm[r]);
  __syncthreads();

  f32x4 o[4];
#pragma unroll
  for (int dt = 0; dt < 4; dt++) o[dt] = (f32x4){0.f, 0.f, 0.f, 0.f};
#pragma unroll
  for (int c5 = 0; c5 < 5; c5++) {
    u16x8 pa = *(const u16x8*)(Ps + m16 * 168 + c5 * 32 + quad * 8);
#pragma unroll
    for (int dt = 0; dt < 4; dt++) {
      u16x8 vb = *(const u16x8*)(Vt + (dt * 16 + m16) * VP_ + w * 16 + c5 * 32 + quad * 8);
      o[dt] = mfma_bf16(pa, vb, o[dt]);
    }
  }
#pragma unroll
  for (int dt = 0; dt < 4; dt++)
#pragma unroll
    for (int r = 0; r < 4; r++)
      out[(size_t)(b * T_ + qw + quad * 4 + r) * D_ + h * HD_ + dt * 16 + m16] =
          f2bf(o[dt][r]);
}

// ---------------------------------------------------------------------------
extern "C" void kernel_launch(void* const* d_in, const int* in_sizes, int n_in,
                              void* d_out, int out_size, void* d_ws, size_t ws_size,
                              hipStream_t stream) {
  (void)in_sizes; (void)n_in; (void)out_size; (void)ws_size;
  const float* x     = (const float*)d_in[0];
  const float* n1w   = (const float*)d_in[1];
  const float* n2w   = (const float*)d_in[2];
  const float* w_qkv = (const float*)d_in[3];
  const float* w_out = (const float*)d_in[4];
  const float* b_out = (const float*)d_in[5];
  const float* w1    = (const float*)d_in[6];
  const float* b1    = (const float*)d_in[7];
  const float* w2    = (const float*)d_in[8];
  const float* b2    = (const float*)d_in[9];
  float* out = (float*)d_out;
  char* ws = (char*)d_ws;

  // workspace layout (x1 bf16; hbuf aliases dead qkv+attno, hn aliases xn)
  u16* wqkvT  = (u16*)(ws + 0);          // [1536][512]  1.5 MB
  u16* woutT  = (u16*)(ws + 1572864);    // [512][512]   0.5 MB
  u16* w1T    = (u16*)(ws + 2097152);    // [2048][512]  2 MB
  u16* w2T    = (u16*)(ws + 4194304);    // [512][2048]  2 MB
  u16* xn     = (u16*)(ws + 6291456);    // [8192][512]  8 MB (also hn)
  u16* qkv    = (u16*)(ws + 14680064);   // [8192][1536] 24 MB
  u16* attno  = (u16*)(ws + 39845888);   // [8192][512]  8 MB
  u16* x1     = (u16*)(ws + 48234496);   // [8192][512]  8 MB bf16
  u16* xbf    = (u16*)(ws + 56623104);   // [8192][512]  8 MB bf16 (raw x)
  u16* hn     = xn;
  u16* hbuf   = qkv;                     // [8192][2048] 32 MB (over qkv+attno)

  trans4_kernel<<<3072, dim3(32, 8), 0, stream>>>(
      w_qkv, wqkvT, w_out, woutT, w1, w1T, w2, w2T);

  // rms1 also emits raw x as bf16 for the w_out residual
  rmsnorm_kernel<false><<<2048, 256, 0, stream>>>(x, n1w, xn, xbf);
  gemm_kernel<64, 128, false, 0, false, true><<<dim3(12, 128), 256, 0, stream>>>(
      xn, wqkvT, (void*)qkv, nullptr, nullptr, M_, 3 * D_, D_);
  attn_kernel<<<dim3(32, 8, 4), 256, 0, stream>>>(qkv, attno);
  // x1 = attno @ w_out + b_out + xbf   (bf16 out, bf16 res)
  gemm_kernel<64, 128, true, 2, false, true><<<dim3(4, 128), 256, 0, stream>>>(
      attno, woutT, (void*)x1, b_out, xbf, M_, D_, D_);
  rmsnorm_kernel<true><<<2048, 256, 0, stream>>>(x1, n2w, hn, nullptr);
  gemm_kernel<64, 128, true, 0, true, true><<<dim3(16, 128), 256, 0, stream>>>(
      hn, w1T, (void*)hbuf, b1, nullptr, M_, FF_, D_);
  // out = hbuf @ w2 + b2 + x1   (f32 out, bf16 res)
  gemm_kernel<64, 128, true, 2, false, false><<<dim3(4, 128), 256, 0, stream>>>(
      hbuf, w2T, (void*)out, b2, x1, M_, D_, FF_);
}

// Round 10
// 222.356 us; speedup vs baseline: 1.0326x; 1.0034x over previous
//
#include <hip/hip_runtime.h>
#include <cstdint>
#include <cstddef>

// ---------------- problem constants (fixed by setup_inputs) ----------------
#define B_  4
#define T_  2048
#define D_  512
#define NH_ 8
#define HD_ 64
#define FF_ 2048
#define M_  (B_*T_)   // 8192 token rows

typedef unsigned short u16;
typedef __attribute__((ext_vector_type(8))) unsigned short u16x8;
typedef __attribute__((ext_vector_type(8))) __bf16         bf16x8;
typedef __attribute__((ext_vector_type(4))) float          f32x4;

__device__ __forceinline__ u16 f2bf(float f) {            // RNE f32 -> bf16
  unsigned u = __float_as_uint(f);
  u += 0x7FFF + ((u >> 16) & 1);
  return (u16)(u >> 16);
}
__device__ __forceinline__ float bf2f(u16 h) {
  return __uint_as_float((unsigned)h << 16);
}

__device__ __forceinline__ f32x4 mfma_bf16(u16x8 a, u16x8 b, f32x4 c) {
  return __builtin_amdgcn_mfma_f32_16x16x32_bf16(
      __builtin_bit_cast(bf16x8, a), __builtin_bit_cast(bf16x8, b), c, 0, 0, 0);
}

// async global->LDS, 16B per lane; LDS dest = wave-uniform base + lane*16
__device__ __forceinline__ void async16(const void* g, void* l) {
  __builtin_amdgcn_global_load_lds(
      (const __attribute__((address_space(1))) unsigned int*)g,
      (__attribute__((address_space(3))) unsigned int*)l, 16, 0, 0);
}

// Branchless GELU via A&S 7.1.26 erf (|err| <= 1.5e-7).
__device__ __forceinline__ float gelu_f(float v) {
  float ax = fabsf(v) * 0.70710678118f;
  float t = 1.0f / (1.0f + 0.3275911f * ax);
  float p = ((((1.061405429f * t - 1.453152027f) * t + 1.421413741f) * t
              - 0.284496736f) * t + 0.254829592f) * t;
  float e = __expf(-ax * ax);
  float er = 1.0f - p * e;
  float s = (v >= 0.0f) ? er : -er;
  return 0.5f * v * (1.0f + s);
}

// ---- fused prep: 4 weight transposes + rmsnorm1 (+raw bf16 x) in ONE launch.
// blocks 0..3071: transpose tiles; blocks 3072..5119: rmsnorm rows.
__global__ __launch_bounds__(256) void prep_kernel(
    const float* __restrict__ i0, u16* __restrict__ o0,   // wqkv 512x1536
    const float* __restrict__ i1, u16* __restrict__ o1,   // wout 512x512
    const float* __restrict__ i2, u16* __restrict__ o2,   // w1   512x2048
    const float* __restrict__ i3, u16* __restrict__ o3,   // w2   2048x512
    const float* __restrict__ x, const float* __restrict__ n1w,
    u16* __restrict__ xn, u16* __restrict__ xbf) {
  __shared__ float tile[32][33];
  const int bid = blockIdx.x, tid = threadIdx.x;
  if (bid < 3072) {
    const float* in; u16* out; int R, C, gx, lb;
    if (bid < 768)       { in = i0; out = o0; R = 512;  C = 1536; gx = 48; lb = bid; }
    else if (bid < 1024) { in = i1; out = o1; R = 512;  C = 512;  gx = 16; lb = bid - 768; }
    else if (bid < 2048) { in = i2; out = o2; R = 512;  C = 2048; gx = 64; lb = bid - 1024; }
    else                 { in = i3; out = o3; R = 2048; C = 512;  gx = 16; lb = bid - 2048; }
    int c0 = (lb % gx) * 32, r0 = (lb / gx) * 32;
    int tx = tid & 31, ty = tid >> 5;  // 32x8
#pragma unroll
    for (int i = 0; i < 4; i++)
      tile[ty + i * 8][tx] = in[(size_t)(r0 + ty + i * 8) * C + c0 + tx];
    __syncthreads();
#pragma unroll
    for (int i = 0; i < 4; i++)
      out[(size_t)(c0 + ty + i * 8) * R + r0 + tx] = f2bf(tile[tx][ty + i * 8]);
  } else {
    int row  = (bid - 3072) * 4 + (tid >> 6);
    int lane = tid & 63;
    const float* xr = x + (size_t)row * D_ + lane * 8;
    float v[8];
    *(float4*)(v)     = *(const float4*)xr;
    *(float4*)(v + 4) = *(const float4*)(xr + 4);
    u16 rw[8];
#pragma unroll
    for (int e = 0; e < 8; e++) rw[e] = f2bf(v[e]);
    *(uint4*)(xbf + (size_t)row * D_ + lane * 8) = *(uint4*)rw;
    float ss = 0.f;
#pragma unroll
    for (int e = 0; e < 8; e++) ss += v[e] * v[e];
#pragma unroll
    for (int m = 1; m < 64; m <<= 1) ss += __shfl_xor(ss, m, 64);
    float inv = rsqrtf(ss * (1.0f / D_) + 1e-6f);
    const float* wr = n1w + lane * 8;
    float wv[8];
    *(float4*)(wv)     = *(const float4*)wr;
    *(float4*)(wv + 4) = *(const float4*)(wr + 4);
    u16 o[8];
#pragma unroll
    for (int e = 0; e < 8; e++) o[e] = f2bf(v[e] * inv * wv[e]);
    *(uint4*)(xn + (size_t)row * D_ + lane * 8) = *(uint4*)o;
  }
}

// ---- rmsnorm over rows of 512, bf16 in -> bf16 out. 1 wave per row.
__global__ __launch_bounds__(256) void rmsnorm_kernel(const u16* __restrict__ xv,
                                                      const float* __restrict__ w,
                                                      u16* __restrict__ out) {
  int row  = blockIdx.x * 4 + (threadIdx.x >> 6);
  int lane = threadIdx.x & 63;
  float v[8];
  u16x8 raw = *(const u16x8*)(xv + (size_t)row * D_ + lane * 8);
#pragma unroll
  for (int e = 0; e < 8; e++) v[e] = bf2f(raw[e]);
  float ss = 0.f;
#pragma unroll
  for (int e = 0; e < 8; e++) ss += v[e] * v[e];
#pragma unroll
  for (int m = 1; m < 64; m <<= 1) ss += __shfl_xor(ss, m, 64);
  float inv = rsqrtf(ss * (1.0f / D_) + 1e-6f);
  const float* wr = w + lane * 8;
  float wv[8];
  *(float4*)(wv)     = *(const float4*)wr;
  *(float4*)(wv + 4) = *(const float4*)(wr + 4);
  u16 o[8];
#pragma unroll
  for (int e = 0; e < 8; e++) o[e] = f2bf(v[e] * inv * wv[e]);
  *(uint4*)(out + (size_t)row * D_ + lane * 8) = *(uint4*)o;
}

// ---- bf16 MFMA GEMM: C[M,N] = A[M,K] * Bt[N,K]^T (+bias)(gelu)(+res)
// BM x BN tile, BK=64, double-buffered LDS, prefetch-after-barrier.
// BM=128/BN=128: wave tile 64x64 (32 MFMA/barrier, 16.4 MAC per LDS byte,
//   64 KB LDS -> 2 blocks/CU) — for the big-N GEMMs (LDS-BW-limited).
// BM=64/BN=128: wave tile 32x64, 48 KB -> 3 blocks/CU — for N=512 GEMMs
//   (occupancy-limited; R5 showed 128-square there collapses to 1 block/CU).
// XOR-swizzled LDS: 16B chunk c (of 8) of row r at physical slot c^(r&7).
// RES_MODE: 0 none, 1 f32, 2 bf16.
template <int BM, int BN, bool HAS_BIAS, int RES_MODE, bool DO_GELU, bool STORE_BF16>
__global__ __launch_bounds__(256) void gemm_kernel(
    const u16* __restrict__ A, const u16* __restrict__ Bt, void* __restrict__ Cv,
    const float* __restrict__ bias, const void* __restrict__ resv,
    int M, int N, int K) {
  constexpr int ACH = BM / 32;              // A staging chunks (32 rows each)
  constexpr int BCH = BN / 32;              // B staging chunks
  constexpr int WM  = BM / 2, WN = BN / 2;  // per-wave tile
  constexpr int MI  = WM / 16, NJ = WN / 16;
  constexpr int EW  = BN + 4;               // epilogue LDS row pitch (f32)
  constexpr int STG = (BM + BN) * 128;      // bytes per stage buffer (A+B)
  constexpr int EPB = 32 * EW * 4;          // epilogue bytes
  constexpr int SMB = (2 * STG > EPB) ? 2 * STG : EPB;
  __shared__ __align__(16) char smem[SMB];
  const int tid = threadIdx.x;
  const int lane = tid & 63, w = tid >> 6;
  const int quad = lane >> 4, m16 = lane & 15;
  const int wm = w & 1, wn = w >> 1;
  const int m0 = blockIdx.y * BM, n0 = blockIdx.x * BN;

  f32x4 acc[MI][NJ];
#pragma unroll
  for (int i = 0; i < MI; i++)
#pragma unroll
    for (int j = 0; j < NJ; j++) acc[i][j] = (f32x4){0.f, 0.f, 0.f, 0.f};

  const int srow = tid >> 3;                       // 0..31
  const int scol = (((tid & 7) ^ (srow & 7))) * 8; // swizzled source k-chunk
  const u16* Ag = A  + (size_t)(m0 + srow) * K + scol;
  const u16* Bg = Bt + (size_t)(n0 + srow) * K + scol;

  auto stage = [&](int buf, int kt) {
    char* base = smem + buf * STG;
#pragma unroll
    for (int c = 0; c < ACH; c++)
      async16(Ag + (size_t)c * 32 * K + kt, base + c * 4096 + tid * 16);
#pragma unroll
    for (int c = 0; c < BCH; c++)
      async16(Bg + (size_t)c * 32 * K + kt, base + BM * 128 + c * 4096 + tid * 16);
  };
  auto compute = [&](int buf) {
    const u16* lA = (const u16*)(smem + buf * STG);
    const u16* lB = (const u16*)(smem + buf * STG + BM * 128);
#pragma unroll
    for (int kk = 0; kk < 2; kk++) {
      const int sl = ((kk * 4 + quad) ^ (m16 & 7)) * 8;  // physical slot
      const u16* pa = lA + (wm * WM + m16) * 64 + sl;
      const u16* pb = lB + (wn * WN + m16) * 64 + sl;
      u16x8 af[MI], bfr[NJ];
#pragma unroll
      for (int i = 0; i < MI; i++) af[i] = *(const u16x8*)(pa + i * 1024);
#pragma unroll
      for (int j = 0; j < NJ; j++) bfr[j] = *(const u16x8*)(pb + j * 1024);
#pragma unroll
      for (int i = 0; i < MI; i++)
#pragma unroll
        for (int j = 0; j < NJ; j++)
          acc[i][j] = mfma_bf16(af[i], bfr[j], acc[i][j]);
    }
  };

  const int nk = K >> 6;
  stage(0, 0);
  for (int t = 0; t < nk; t++) {
    __syncthreads();                // drains stage(t); covered by compute(t-1)
    if (t + 1 < nk) stage((t + 1) & 1, (t + 1) << 6);
    compute(t & 1);
  }

  // ---- epilogue: stage 32 rows x BN cols f32 in LDS per i-step, then
  // read back row-major and store full vectors (no partial lines).
  float* eps = (float*)smem;
  constexpr int REPS = (32 * BN) / (256 * 8);   // 2 for BN=128, 1 for BN=64
  float bv[REPS > 0 ? REPS : 1][8];
  if (HAS_BIAS) {
#pragma unroll
    for (int rep = 0; rep < REPS; rep++) {
      const int col = (BN == 128) ? ((tid & 15) * 8) : ((tid & 7) * 8);
      *(float4*)(bv[rep])     = *(const float4*)(bias + n0 + col);
      *(float4*)(bv[rep] + 4) = *(const float4*)(bias + n0 + col + 4);
    }
  }
#pragma unroll
  for (int i = 0; i < MI; i++) {
    __syncthreads();
#pragma unroll
    for (int j = 0; j < NJ; j++)
#pragma unroll
      for (int r = 0; r < 4; r++)
        eps[(wm * 16 + quad * 4 + r) * EW + wn * WN + j * 16 + m16] =
            acc[i][j][r];
    __syncthreads();
#pragma unroll
    for (int rep = 0; rep < REPS; rep++) {
      const int lr  = (BN == 128) ? (rep * 16 + (tid >> 4)) : (tid >> 3);
      const int col = (BN == 128) ? ((tid & 15) * 8) : ((tid & 7) * 8);
      const int rg  = m0 + (lr >> 4) * WM + i * 16 + (lr & 15);
      float v[8];
      *(float4*)(v)     = *(const float4*)(eps + lr * EW + col);
      *(float4*)(v + 4) = *(const float4*)(eps + lr * EW + col + 4);
      if (HAS_BIAS) {
#pragma unroll
        for (int e = 0; e < 8; e++) v[e] += bv[rep][e];
      }
      if (DO_GELU) {
#pragma unroll
        for (int e = 0; e < 8; e++) v[e] = gelu_f(v[e]);
      }
      const size_t idx = (size_t)rg * N + n0 + col;
      if (RES_MODE == 1) {
        float4 r0 = *(const float4*)((const float*)resv + idx);
        float4 r1 = *(const float4*)((const float*)resv + idx + 4);
        v[0] += r0.x; v[1] += r0.y; v[2] += r0.z; v[3] += r0.w;
        v[4] += r1.x; v[5] += r1.y; v[6] += r1.z; v[7] += r1.w;
      } else if (RES_MODE == 2) {
        u16x8 rr = *(const u16x8*)((const u16*)resv + idx);
#pragma unroll
        for (int e = 0; e < 8; e++) v[e] += bf2f(rr[e]);
      }
      if (STORE_BF16) {
        u16 o[8];
#pragma unroll
        for (int e = 0; e < 8; e++) o[e] = f2bf(v[e]);
        *(uint4*)((u16*)Cv + idx) = *(uint4*)o;
      } else {
        *(float4*)((float*)Cv + idx)     = *(float4*)(v);
        *(float4*)((float*)Cv + idx + 4) = *(float4*)(v + 4);
      }
    }
  }
}

// ---- banded attention, MFMA flash-style, full-window softmax in registers.
#define KP_ 72
#define VP_ 218
__global__ __launch_bounds__(256) void attn_kernel(const u16* __restrict__ qkv,
                                                   u16* __restrict__ out) {
  __shared__ __align__(16) char smem[29952 + 64 * VP_ * 2];
  u16* Ks = (u16*)smem;               // [208][72] keys (29952 B)
  u16* Vt = (u16*)(smem + 29952);     // [64][218] V transposed
  const int tid = threadIdx.x, lane = tid & 63, w = tid >> 6;
  const int quad = lane >> 4, m16 = lane & 15;
  const int q0 = blockIdx.x * 64, h = blockIdx.y, b = blockIdx.z;
  const int kstart = q0 - 64;         // 208-key staging window
  const u16* base = qkv + (size_t)b * T_ * 1536;

  for (int c = tid; c < 1664; c += 256) {
    int row = c >> 3, cc = (c & 7) * 8;
    int j = kstart + row;
    j = j < 0 ? 0 : (j > T_ - 1 ? T_ - 1 : j);   // clamp; masked later
    *(uint4*)(Ks + row * KP_ + cc) =
        *(const uint4*)(base + (size_t)j * 1536 + 512 + h * 64 + cc);
  }
  for (int c = tid; c < 1664; c += 256) {
    int row = c >> 3, cc = (c & 7) * 8;
    int j = kstart + row;
    j = j < 0 ? 0 : (j > T_ - 1 ? T_ - 1 : j);
    uint4 u = *(const uint4*)(base + (size_t)j * 1536 + 1024 + h * 64 + cc);
    u16 tmp[8];
    *(uint4*)tmp = u;
#pragma unroll
    for (int i = 0; i < 8; i++) Vt[(cc + i) * VP_ + row] = tmp[i];
  }
  const int qw = q0 + w * 16;
  const u16* qb = base + (size_t)(qw + m16) * 1536 + h * 64 + quad * 8;
  u16x8 a0 = *(const u16x8*)qb;
  u16x8 a1 = *(const u16x8*)(qb + 32);
  __syncthreads();

  float s[10][4];
#pragma unroll
  for (int t = 0; t < 10; t++) {
    int kt = (w + t) * 16;
    u16x8 kb0 = *(const u16x8*)(Ks + (kt + m16) * KP_ + quad * 8);
    u16x8 kb1 = *(const u16x8*)(Ks + (kt + m16) * KP_ + 32 + quad * 8);
    f32x4 acc = {0.f, 0.f, 0.f, 0.f};
    acc = mfma_bf16(a0, kb0, acc);
    acc = mfma_bf16(a1, kb1, acc);
    int jab = kstart + kt + m16;
#pragma unroll
    for (int r = 0; r < 4; r++) {
      int q = qw + quad * 4 + r;
      int d = q - jab;
      bool valid = (jab >= 0) && (jab < T_) && (d <= 64) && (d >= -64);
      s[t][r] = valid ? acc[r] * 0.125f : -1e30f;
    }
  }
  float mx[4], sm[4];
#pragma unroll
  for (int r = 0; r < 4; r++) mx[r] = -1e30f;
#pragma unroll
  for (int t = 0; t < 10; t++)
#pragma unroll
    for (int r = 0; r < 4; r++) mx[r] = fmaxf(mx[r], s[t][r]);
#pragma unroll
  for (int r = 0; r < 4; r++) {
#pragma unroll
    for (int msk = 1; msk < 16; msk <<= 1)
      mx[r] = fmaxf(mx[r], __shfl_xor(mx[r], msk, 64));
    sm[r] = 0.f;
  }
#pragma unroll
  for (int t = 0; t < 10; t++)
#pragma unroll
    for (int r = 0; r < 4; r++) {
      float e = __expf(s[t][r] - mx[r]);
      s[t][r] = e; sm[r] += e;
    }
#pragma unroll
  for (int r = 0; r < 4; r++) {
#pragma unroll
    for (int msk = 1; msk < 16; msk <<= 1) sm[r] += __shfl_xor(sm[r], msk, 64);
    sm[r] = 1.0f / sm[r];
  }
  __syncthreads();
  u16* Ps = (u16*)smem + w * 2688;       // alias Ks region: per-wave [16][168]
#pragma unroll
  for (int t = 0; t < 10; t++)
#pragma unroll
    for (int r = 0; r < 4; r++)
      Ps[(quad * 4 + r) * 168 + t * 16 + m16] = f2bf(s[t][r] * sm[r]);
  __syncthreads();

  f32x4 o[4];
#pragma unroll
  for (int dt = 0; dt < 4; dt++) o[dt] = (f32x4){0.f, 0.f, 0.f, 0.f};
#pragma unroll
  for (int c5 = 0; c5 < 5; c5++) {
    u16x8 pa = *(const u16x8*)(Ps + m16 * 168 + c5 * 32 + quad * 8);
#pragma unroll
    for (int dt = 0; dt < 4; dt++) {
      u16x8 vb = *(const u16x8*)(Vt + (dt * 16 + m16) * VP_ + w * 16 + c5 * 32 + quad * 8);
      o[dt] = mfma_bf16(pa, vb, o[dt]);
    }
  }
#pragma unroll
  for (int dt = 0; dt < 4; dt++)
#pragma unroll
    for (int r = 0; r < 4; r++)
      out[(size_t)(b * T_ + qw + quad * 4 + r) * D_ + h * HD_ + dt * 16 + m16] =
          f2bf(o[dt][r]);
}

// ---------------------------------------------------------------------------
extern "C" void kernel_launch(void* const* d_in, const int* in_sizes, int n_in,
                              void* d_out, int out_size, void* d_ws, size_t ws_size,
                              hipStream_t stream) {
  (void)in_sizes; (void)n_in; (void)out_size; (void)ws_size;
  const float* x     = (const float*)d_in[0];
  const float* n1w   = (const float*)d_in[1];
  const float* n2w   = (const float*)d_in[2];
  const float* w_qkv = (const float*)d_in[3];
  const float* w_out = (const float*)d_in[4];
  const float* b_out = (const float*)d_in[5];
  const float* w1    = (const float*)d_in[6];
  const float* b1    = (const float*)d_in[7];
  const float* w2    = (const float*)d_in[8];
  const float* b2    = (const float*)d_in[9];
  float* out = (float*)d_out;
  char* ws = (char*)d_ws;

  // workspace layout (x1 bf16; hbuf aliases dead qkv+attno, hn aliases xn)
  u16* wqkvT  = (u16*)(ws + 0);          // [1536][512]  1.5 MB
  u16* woutT  = (u16*)(ws + 1572864);    // [512][512]   0.5 MB
  u16* w1T    = (u16*)(ws + 2097152);    // [2048][512]  2 MB
  u16* w2T    = (u16*)(ws + 4194304);    // [512][2048]  2 MB
  u16* xn     = (u16*)(ws + 6291456);    // [8192][512]  8 MB (also hn)
  u16* qkv    = (u16*)(ws + 14680064);   // [8192][1536] 24 MB
  u16* attno  = (u16*)(ws + 39845888);   // [8192][512]  8 MB
  u16* x1     = (u16*)(ws + 48234496);   // [8192][512]  8 MB bf16
  u16* xbf    = (u16*)(ws + 56623104);   // [8192][512]  8 MB bf16 (raw x)
  u16* hn     = xn;
  u16* hbuf   = qkv;                     // [8192][2048] 32 MB (over qkv+attno)

  // fused: weight transposes + rmsnorm1 (+xbf emit)
  prep_kernel<<<5120, 256, 0, stream>>>(
      w_qkv, wqkvT, w_out, woutT, w1, w1T, w2, w2T, x, n1w, xn, xbf);

  // qkv = xn @ wqkv   (128x128 tile: LDS-BW-optimal wave 64x64)
  gemm_kernel<128, 128, false, 0, false, true><<<dim3(12, 64), 256, 0, stream>>>(
      xn, wqkvT, (void*)qkv, nullptr, nullptr, M_, 3 * D_, D_);
  attn_kernel<<<dim3(32, 8, 4), 256, 0, stream>>>(qkv, attno);
  // x1 = attno @ w_out + b_out + xbf   (bf16 out, bf16 res; 64x128: occupancy)
  gemm_kernel<64, 128, true, 2, false, true><<<dim3(4, 128), 256, 0, stream>>>(
      attno, woutT, (void*)x1, b_out, xbf, M_, D_, D_);
  rmsnorm_kernel<<<2048, 256, 0, stream>>>(x1, n2w, hn);
  // hbuf = gelu(hn @ w1 + b1)   (128x128 tile)
  gemm_kernel<128, 128, true, 0, true, true><<<dim3(16, 64), 256, 0, stream>>>(
      hn, w1T, (void*)hbuf, b1, nullptr, M_, FF_, D_);
  // out = hbuf @ w2 + b2 + x1   (f32 out, bf16 res; 64x128: occupancy)
  gemm_kernel<64, 128, true, 2, false, false><<<dim3(4, 128), 256, 0, stream>>>(
      hbuf, w2T, (void*)out, b2, x1, M_, D_, FF_);
}

// Round 11
// 214.425 us; speedup vs baseline: 1.0708x; 1.0370x over previous
//
#include <hip/hip_runtime.h>
#include <cstdint>
#include <cstddef>

// ---------------- problem constants (fixed by setup_inputs) ----------------
#define B_  4
#define T_  2048
#define D_  512
#define NH_ 8
#define HD_ 64
#define FF_ 2048
#define M_  (B_*T_)   // 8192 token rows

typedef unsigned short u16;
typedef __attribute__((ext_vector_type(8))) unsigned short u16x8;
typedef __attribute__((ext_vector_type(8))) __bf16         bf16x8;
typedef __attribute__((ext_vector_type(4))) float          f32x4;

__device__ __forceinline__ u16 f2bf(float f) {            // RNE f32 -> bf16
  unsigned u = __float_as_uint(f);
  u += 0x7FFF + ((u >> 16) & 1);
  return (u16)(u >> 16);
}
__device__ __forceinline__ float bf2f(u16 h) {
  return __uint_as_float((unsigned)h << 16);
}

__device__ __forceinline__ f32x4 mfma_bf16(u16x8 a, u16x8 b, f32x4 c) {
  return __builtin_amdgcn_mfma_f32_16x16x32_bf16(
      __builtin_bit_cast(bf16x8, a), __builtin_bit_cast(bf16x8, b), c, 0, 0, 0);
}

// async global->LDS, 16B per lane; LDS dest = wave-uniform base + lane*16
__device__ __forceinline__ void async16(const void* g, void* l) {
  __builtin_amdgcn_global_load_lds(
      (const __attribute__((address_space(1))) unsigned int*)g,
      (__attribute__((address_space(3))) unsigned int*)l, 16, 0, 0);
}

// Branchless GELU via A&S 7.1.26 erf (|err| <= 1.5e-7).
__device__ __forceinline__ float gelu_f(float v) {
  float ax = fabsf(v) * 0.70710678118f;
  float t = 1.0f / (1.0f + 0.3275911f * ax);
  float p = ((((1.061405429f * t - 1.453152027f) * t + 1.421413741f) * t
              - 0.284496736f) * t + 0.254829592f) * t;
  float e = __expf(-ax * ax);
  float er = 1.0f - p * e;
  float s = (v >= 0.0f) ? er : -er;
  return 0.5f * v * (1.0f + s);
}

// ---- fused prep: 4 weight transposes + rmsnorm1 (+raw bf16 x) in ONE launch.
// blocks 0..3071: transpose tiles; blocks 3072..5119: rmsnorm rows.
__global__ __launch_bounds__(256) void prep_kernel(
    const float* __restrict__ i0, u16* __restrict__ o0,   // wqkv 512x1536
    const float* __restrict__ i1, u16* __restrict__ o1,   // wout 512x512
    const float* __restrict__ i2, u16* __restrict__ o2,   // w1   512x2048
    const float* __restrict__ i3, u16* __restrict__ o3,   // w2   2048x512
    const float* __restrict__ x, const float* __restrict__ n1w,
    u16* __restrict__ xn, u16* __restrict__ xbf) {
  __shared__ float tile[32][33];
  const int bid = blockIdx.x, tid = threadIdx.x;
  if (bid < 3072) {
    const float* in; u16* out; int R, C, gx, lb;
    if (bid < 768)       { in = i0; out = o0; R = 512;  C = 1536; gx = 48; lb = bid; }
    else if (bid < 1024) { in = i1; out = o1; R = 512;  C = 512;  gx = 16; lb = bid - 768; }
    else if (bid < 2048) { in = i2; out = o2; R = 512;  C = 2048; gx = 64; lb = bid - 1024; }
    else                 { in = i3; out = o3; R = 2048; C = 512;  gx = 16; lb = bid - 2048; }
    int c0 = (lb % gx) * 32, r0 = (lb / gx) * 32;
    int tx = tid & 31, ty = tid >> 5;  // 32x8
#pragma unroll
    for (int i = 0; i < 4; i++)
      tile[ty + i * 8][tx] = in[(size_t)(r0 + ty + i * 8) * C + c0 + tx];
    __syncthreads();
#pragma unroll
    for (int i = 0; i < 4; i++)
      out[(size_t)(c0 + ty + i * 8) * R + r0 + tx] = f2bf(tile[tx][ty + i * 8]);
  } else {
    int row  = (bid - 3072) * 4 + (tid >> 6);
    int lane = tid & 63;
    const float* xr = x + (size_t)row * D_ + lane * 8;
    float v[8];
    *(float4*)(v)     = *(const float4*)xr;
    *(float4*)(v + 4) = *(const float4*)(xr + 4);
    u16 rw[8];
#pragma unroll
    for (int e = 0; e < 8; e++) rw[e] = f2bf(v[e]);
    *(uint4*)(xbf + (size_t)row * D_ + lane * 8) = *(uint4*)rw;
    float ss = 0.f;
#pragma unroll
    for (int e = 0; e < 8; e++) ss += v[e] * v[e];
#pragma unroll
    for (int m = 1; m < 64; m <<= 1) ss += __shfl_xor(ss, m, 64);
    float inv = rsqrtf(ss * (1.0f / D_) + 1e-6f);
    const float* wr = n1w + lane * 8;
    float wv[8];
    *(float4*)(wv)     = *(const float4*)wr;
    *(float4*)(wv + 4) = *(const float4*)(wr + 4);
    u16 o[8];
#pragma unroll
    for (int e = 0; e < 8; e++) o[e] = f2bf(v[e] * inv * wv[e]);
    *(uint4*)(xn + (size_t)row * D_ + lane * 8) = *(uint4*)o;
  }
}

// ---- rmsnorm over rows of 512, bf16 in -> bf16 out. 1 wave per row.
__global__ __launch_bounds__(256) void rmsnorm_kernel(const u16* __restrict__ xv,
                                                      const float* __restrict__ w,
                                                      u16* __restrict__ out) {
  int row  = blockIdx.x * 4 + (threadIdx.x >> 6);
  int lane = threadIdx.x & 63;
  float v[8];
  u16x8 raw = *(const u16x8*)(xv + (size_t)row * D_ + lane * 8);
#pragma unroll
  for (int e = 0; e < 8; e++) v[e] = bf2f(raw[e]);
  float ss = 0.f;
#pragma unroll
  for (int e = 0; e < 8; e++) ss += v[e] * v[e];
#pragma unroll
  for (int m = 1; m < 64; m <<= 1) ss += __shfl_xor(ss, m, 64);
  float inv = rsqrtf(ss * (1.0f / D_) + 1e-6f);
  const float* wr = w + lane * 8;
  float wv[8];
  *(float4*)(wv)     = *(const float4*)wr;
  *(float4*)(wv + 4) = *(const float4*)(wr + 4);
  u16 o[8];
#pragma unroll
  for (int e = 0; e < 8; e++) o[e] = f2bf(v[e] * inv * wv[e]);
  *(uint4*)(out + (size_t)row * D_ + lane * 8) = *(uint4*)o;
}

// ---- bf16 MFMA GEMM: C[M,N] = A[M,K] * Bt[N,K]^T (+bias)(gelu)(+res)
// BM x BN tile, BK=64, double-buffered LDS, prefetch-after-barrier.
// 128x128 (wave 64x64): best MAC/LDS-byte, 2 blocks/CU — use when grid
//   gives full rounds (w1: 1024 blocks). 64x128 (wave 32x64): 3 blocks/CU —
//   use for N=512 GEMMs and qkv (1536 blocks -> 2 full rounds, no tail).
// XOR-swizzled LDS: 16B chunk c (of 8) of row r at physical slot c^(r&7).
// RES_MODE: 0 none, 1 f32, 2 bf16.
template <int BM, int BN, bool HAS_BIAS, int RES_MODE, bool DO_GELU, bool STORE_BF16>
__global__ __launch_bounds__(256) void gemm_kernel(
    const u16* __restrict__ A, const u16* __restrict__ Bt, void* __restrict__ Cv,
    const float* __restrict__ bias, const void* __restrict__ resv,
    int M, int N, int K) {
  constexpr int ACH = BM / 32;              // A staging chunks (32 rows each)
  constexpr int BCH = BN / 32;              // B staging chunks
  constexpr int WM  = BM / 2, WN = BN / 2;  // per-wave tile
  constexpr int MI  = WM / 16, NJ = WN / 16;
  constexpr int EW  = BN + 4;               // epilogue LDS row pitch (f32)
  constexpr int STG = (BM + BN) * 128;      // bytes per stage buffer (A+B)
  constexpr int EPB = 32 * EW * 4;          // epilogue bytes
  constexpr int SMB = (2 * STG > EPB) ? 2 * STG : EPB;
  __shared__ __align__(16) char smem[SMB];
  const int tid = threadIdx.x;
  const int lane = tid & 63, w = tid >> 6;
  const int quad = lane >> 4, m16 = lane & 15;
  const int wm = w & 1, wn = w >> 1;
  const int m0 = blockIdx.y * BM, n0 = blockIdx.x * BN;

  f32x4 acc[MI][NJ];
#pragma unroll
  for (int i = 0; i < MI; i++)
#pragma unroll
    for (int j = 0; j < NJ; j++) acc[i][j] = (f32x4){0.f, 0.f, 0.f, 0.f};

  const int srow = tid >> 3;                       // 0..31
  const int scol = (((tid & 7) ^ (srow & 7))) * 8; // swizzled source k-chunk
  const u16* Ag = A  + (size_t)(m0 + srow) * K + scol;
  const u16* Bg = Bt + (size_t)(n0 + srow) * K + scol;

  auto stage = [&](int buf, int kt) {
    char* base = smem + buf * STG;
#pragma unroll
    for (int c = 0; c < ACH; c++)
      async16(Ag + (size_t)c * 32 * K + kt, base + c * 4096 + tid * 16);
#pragma unroll
    for (int c = 0; c < BCH; c++)
      async16(Bg + (size_t)c * 32 * K + kt, base + BM * 128 + c * 4096 + tid * 16);
  };
  auto compute = [&](int buf) {
    const u16* lA = (const u16*)(smem + buf * STG);
    const u16* lB = (const u16*)(smem + buf * STG + BM * 128);
#pragma unroll
    for (int kk = 0; kk < 2; kk++) {
      const int sl = ((kk * 4 + quad) ^ (m16 & 7)) * 8;  // physical slot
      const u16* pa = lA + (wm * WM + m16) * 64 + sl;
      const u16* pb = lB + (wn * WN + m16) * 64 + sl;
      u16x8 af[MI], bfr[NJ];
#pragma unroll
      for (int i = 0; i < MI; i++) af[i] = *(const u16x8*)(pa + i * 1024);
#pragma unroll
      for (int j = 0; j < NJ; j++) bfr[j] = *(const u16x8*)(pb + j * 1024);
#pragma unroll
      for (int i = 0; i < MI; i++)
#pragma unroll
        for (int j = 0; j < NJ; j++)
          acc[i][j] = mfma_bf16(af[i], bfr[j], acc[i][j]);
    }
  };

  const int nk = K >> 6;
  stage(0, 0);
  for (int t = 0; t < nk; t++) {
    __syncthreads();                // drains stage(t); covered by compute(t-1)
    if (t + 1 < nk) stage((t + 1) & 1, (t + 1) << 6);
    compute(t & 1);
  }

  // ---- epilogue: stage 32 rows x BN cols f32 in LDS per i-step, then
  // read back row-major and store full vectors (no partial lines).
  float* eps = (float*)smem;
  constexpr int REPS = (32 * BN) / (256 * 8);   // 2 for BN=128, 1 for BN=64
  float bv[REPS > 0 ? REPS : 1][8];
  if (HAS_BIAS) {
#pragma unroll
    for (int rep = 0; rep < REPS; rep++) {
      const int col = (BN == 128) ? ((tid & 15) * 8) : ((tid & 7) * 8);
      *(float4*)(bv[rep])     = *(const float4*)(bias + n0 + col);
      *(float4*)(bv[rep] + 4) = *(const float4*)(bias + n0 + col + 4);
    }
  }
#pragma unroll
  for (int i = 0; i < MI; i++) {
    __syncthreads();
#pragma unroll
    for (int j = 0; j < NJ; j++)
#pragma unroll
      for (int r = 0; r < 4; r++)
        eps[(wm * 16 + quad * 4 + r) * EW + wn * WN + j * 16 + m16] =
            acc[i][j][r];
    __syncthreads();
#pragma unroll
    for (int rep = 0; rep < REPS; rep++) {
      const int lr  = (BN == 128) ? (rep * 16 + (tid >> 4)) : (tid >> 3);
      const int col = (BN == 128) ? ((tid & 15) * 8) : ((tid & 7) * 8);
      const int rg  = m0 + (lr >> 4) * WM + i * 16 + (lr & 15);
      float v[8];
      *(float4*)(v)     = *(const float4*)(eps + lr * EW + col);
      *(float4*)(v + 4) = *(const float4*)(eps + lr * EW + col + 4);
      if (HAS_BIAS) {
#pragma unroll
        for (int e = 0; e < 8; e++) v[e] += bv[rep][e];
      }
      if (DO_GELU) {
#pragma unroll
        for (int e = 0; e < 8; e++) v[e] = gelu_f(v[e]);
      }
      const size_t idx = (size_t)rg * N + n0 + col;
      if (RES_MODE == 1) {
        float4 r0 = *(const float4*)((const float*)resv + idx);
        float4 r1 = *(const float4*)((const float*)resv + idx + 4);
        v[0] += r0.x; v[1] += r0.y; v[2] += r0.z; v[3] += r0.w;
        v[4] += r1.x; v[5] += r1.y; v[6] += r1.z; v[7] += r1.w;
      } else if (RES_MODE == 2) {
        u16x8 rr = *(const u16x8*)((const u16*)resv + idx);
#pragma unroll
        for (int e = 0; e < 8; e++) v[e] += bf2f(rr[e]);
      }
      if (STORE_BF16) {
        u16 o[8];
#pragma unroll
        for (int e = 0; e < 8; e++) o[e] = f2bf(v[e]);
        *(uint4*)((u16*)Cv + idx) = *(uint4*)o;
      } else {
        *(float4*)((float*)Cv + idx)     = *(float4*)(v);
        *(float4*)((float*)Cv + idx + 4) = *(float4*)(v + 4);
      }
    }
  }
}

// ---- banded attention, MFMA flash-style, full-window softmax in registers.
// LDS repack for 3 blocks/CU (was 57.8 KB -> 2/CU): Ks [208][64] with XOR
// chunk swizzle (chunk c of row r at slot c^(r&7); reads land 8 slots x 2
// lanes = 2-way = free), Vt pitch 216 (dword stride 12 mod 32, conflict-ok).
// Total 26624 + 27648 = 54272 B <= 160KB/3.
#define VP_ 216
__global__ __launch_bounds__(256) void attn_kernel(const u16* __restrict__ qkv,
                                                   u16* __restrict__ out) {
  __shared__ __align__(16) char smem[26624 + 64 * VP_ * 2];
  u16* Ks = (u16*)smem;               // [208][64] keys, swizzled (26624 B)
  u16* Vt = (u16*)(smem + 26624);     // [64][216] V transposed (27648 B)
  const int tid = threadIdx.x, lane = tid & 63, w = tid >> 6;
  const int quad = lane >> 4, m16 = lane & 15;
  const int q0 = blockIdx.x * 64, h = blockIdx.y, b = blockIdx.z;
  const int kstart = q0 - 64;         // 208-key staging window
  const u16* base = qkv + (size_t)b * T_ * 1536;

  for (int c = tid; c < 1664; c += 256) {
    int row = c >> 3, ch = c & 7;
    int j = kstart + row;
    j = j < 0 ? 0 : (j > T_ - 1 ? T_ - 1 : j);   // clamp; masked later
    *(uint4*)(Ks + row * 64 + ((ch ^ (row & 7)) * 8)) =
        *(const uint4*)(base + (size_t)j * 1536 + 512 + h * 64 + ch * 8);
  }
  for (int c = tid; c < 1664; c += 256) {
    int row = c >> 3, cc = (c & 7) * 8;
    int j = kstart + row;
    j = j < 0 ? 0 : (j > T_ - 1 ? T_ - 1 : j);
    uint4 u = *(const uint4*)(base + (size_t)j * 1536 + 1024 + h * 64 + cc);
    u16 tmp[8];
    *(uint4*)tmp = u;
#pragma unroll
    for (int i = 0; i < 8; i++) Vt[(cc + i) * VP_ + row] = tmp[i];
  }
  const int qw = q0 + w * 16;
  const u16* qb = base + (size_t)(qw + m16) * 1536 + h * 64 + quad * 8;
  u16x8 a0 = *(const u16x8*)qb;
  u16x8 a1 = *(const u16x8*)(qb + 32);
  __syncthreads();

  float s[10][4];
#pragma unroll
  for (int t = 0; t < 10; t++) {
    int kt = (w + t) * 16;
    int kr = kt + m16, sw = kr & 7;
    u16x8 kb0 = *(const u16x8*)(Ks + kr * 64 + ((quad ^ sw) * 8));
    u16x8 kb1 = *(const u16x8*)(Ks + kr * 64 + (((4 + quad) ^ sw) * 8));
    f32x4 acc = {0.f, 0.f, 0.f, 0.f};
    acc = mfma_bf16(a0, kb0, acc);
    acc = mfma_bf16(a1, kb1, acc);
    int jab = kstart + kt + m16;
#pragma unroll
    for (int r = 0; r < 4; r++) {
      int q = qw + quad * 4 + r;
      int d = q - jab;
      bool valid = (jab >= 0) && (jab < T_) && (d <= 64) && (d >= -64);
      s[t][r] = valid ? acc[r] * 0.125f : -1e30f;
    }
  }
  float mx[4], sm[4];
#pragma unroll
  for (int r = 0; r < 4; r++) mx[r] = -1e30f;
#pragma unroll
  for (int t = 0; t < 10; t++)
#pragma unroll
    for (int r = 0; r < 4; r++) mx[r] = fmaxf(mx[r], s[t][r]);
#pragma unroll
  for (int r = 0; r < 4; r++) {
#pragma unroll
    for (int msk = 1; msk < 16; msk <<= 1)
      mx[r] = fmaxf(mx[r], __shfl_xor(mx[r], msk, 64));
    sm[r] = 0.f;
  }
#pragma unroll
  for (int t = 0; t < 10; t++)
#pragma unroll
    for (int r = 0; r < 4; r++) {
      float e = __expf(s[t][r] - mx[r]);
      s[t][r] = e; sm[r] += e;
    }
#pragma unroll
  for (int r = 0; r < 4; r++) {
#pragma unroll
    for (int msk = 1; msk < 16; msk <<= 1) sm[r] += __shfl_xor(sm[r], msk, 64);
    sm[r] = 1.0f / sm[r];
  }
  __syncthreads();
  u16* Ps = (u16*)smem + w * 2688;       // alias Ks region: per-wave [16][168]
#pragma unroll
  for (int t = 0; t < 10; t++)
#pragma unroll
    for (int r = 0; r < 4; r++)
      Ps[(quad * 4 + r) * 168 + t * 16 + m16] = f2bf(s[t][r] * sm[r]);
  __syncthreads();

  f32x4 o[4];
#pragma unroll
  for (int dt = 0; dt < 4; dt++) o[dt] = (f32x4){0.f, 0.f, 0.f, 0.f};
#pragma unroll
  for (int c5 = 0; c5 < 5; c5++) {
    u16x8 pa = *(const u16x8*)(Ps + m16 * 168 + c5 * 32 + quad * 8);
#pragma unroll
    for (int dt = 0; dt < 4; dt++) {
      u16x8 vb = *(const u16x8*)(Vt + (dt * 16 + m16) * VP_ + w * 16 + c5 * 32 + quad * 8);
      o[dt] = mfma_bf16(pa, vb, o[dt]);
    }
  }
#pragma unroll
  for (int dt = 0; dt < 4; dt++)
#pragma unroll
    for (int r = 0; r < 4; r++)
      out[(size_t)(b * T_ + qw + quad * 4 + r) * D_ + h * HD_ + dt * 16 + m16] =
          f2bf(o[dt][r]);
}

// ---------------------------------------------------------------------------
extern "C" void kernel_launch(void* const* d_in, const int* in_sizes, int n_in,
                              void* d_out, int out_size, void* d_ws, size_t ws_size,
                              hipStream_t stream) {
  (void)in_sizes; (void)n_in; (void)out_size; (void)ws_size;
  const float* x     = (const float*)d_in[0];
  const float* n1w   = (const float*)d_in[1];
  const float* n2w   = (const float*)d_in[2];
  const float* w_qkv = (const float*)d_in[3];
  const float* w_out = (const float*)d_in[4];
  const float* b_out = (const float*)d_in[5];
  const float* w1    = (const float*)d_in[6];
  const float* b1    = (const float*)d_in[7];
  const float* w2    = (const float*)d_in[8];
  const float* b2    = (const float*)d_in[9];
  float* out = (float*)d_out;
  char* ws = (char*)d_ws;

  // workspace layout (x1 bf16; hbuf aliases dead qkv+attno, hn aliases xn)
  u16* wqkvT  = (u16*)(ws + 0);          // [1536][512]  1.5 MB
  u16* woutT  = (u16*)(ws + 1572864);    // [512][512]   0.5 MB
  u16* w1T    = (u16*)(ws + 2097152);    // [2048][512]  2 MB
  u16* w2T    = (u16*)(ws + 4194304);    // [512][2048]  2 MB
  u16* xn     = (u16*)(ws + 6291456);    // [8192][512]  8 MB (also hn)
  u16* qkv    = (u16*)(ws + 14680064);   // [8192][1536] 24 MB
  u16* attno  = (u16*)(ws + 39845888);   // [8192][512]  8 MB
  u16* x1     = (u16*)(ws + 48234496);   // [8192][512]  8 MB bf16
  u16* xbf    = (u16*)(ws + 56623104);   // [8192][512]  8 MB bf16 (raw x)
  u16* hn     = xn;
  u16* hbuf   = qkv;                     // [8192][2048] 32 MB (over qkv+attno)

  // fused: weight transposes + rmsnorm1 (+xbf emit)
  prep_kernel<<<5120, 256, 0, stream>>>(
      w_qkv, wqkvT, w_out, woutT, w1, w1T, w2, w2T, x, n1w, xn, xbf);

  // qkv = xn @ wqkv   (64x128: 1536 blocks @3/CU = 2 full rounds, no tail)
  gemm_kernel<64, 128, false, 0, false, true><<<dim3(12, 128), 256, 0, stream>>>(
      xn, wqkvT, (void*)qkv, nullptr, nullptr, M_, 3 * D_, D_);
  attn_kernel<<<dim3(32, 8, 4), 256, 0, stream>>>(qkv, attno);
  // x1 = attno @ w_out + b_out + xbf   (bf16 out, bf16 res)
  gemm_kernel<64, 128, true, 2, false, true><<<dim3(4, 128), 256, 0, stream>>>(
      attno, woutT, (void*)x1, b_out, xbf, M_, D_, D_);
  rmsnorm_kernel<<<2048, 256, 0, stream>>>(x1, n2w, hn);
  // hbuf = gelu(hn @ w1 + b1)   (128x128: 1024 blocks @2/CU = 2 full rounds)
  gemm_kernel<128, 128, true, 0, true, true><<<dim3(16, 64), 256, 0, stream>>>(
      hn, w1T, (void*)hbuf, b1, nullptr, M_, FF_, D_);
  // out = hbuf @ w2 + b2 + x1   (f32 out, bf16 res)
  gemm_kernel<64, 128, true, 2, false, false><<<dim3(4, 128), 256, 0, stream>>>(
      hbuf, w2T, (void*)out, b2, x1, M_, D_, FF_);
}